// Round 3
// baseline (123.853 us; speedup 1.0000x reference)
//
#include <hip/hip_runtime.h>
#include <hip/hip_bf16.h>
#include <stdint.h>

#define BB 64
#define TT 16
#define ROWS 1024
#define ADIM 32
#define HID 1536
#define NCAT 4
#define MT_MAX 20          // worst case sum ceil(cnt_c/4) = 19
#define KP 768             // K-range per block (both layers)
#define NTILES (KP/64)     // 12 K-steps of BK=64

typedef __attribute__((ext_vector_type(8))) short bf16x8;
typedef __attribute__((ext_vector_type(4))) float f32x4;

static __device__ __forceinline__ unsigned short f2bf(float f) {
    union { float f; unsigned int u; } v; v.f = f;
    unsigned int u = v.u + 0x7fff + ((v.u >> 16) & 1);   // RNE
    return (unsigned short)(u >> 16);
}

// ---------------------------------------------------------------------------
// prep: group samples by category into padded 4-sample m-tiles.
// ---------------------------------------------------------------------------
__global__ void prep_kernel(const int* __restrict__ cat_ids,
                            int* __restrict__ msample, int* __restrict__ mcat) {
    __shared__ int counts[NCAT];
    const int t = threadIdx.x;
    if (t < NCAT) {
        int c = 0;
        for (int s = 0; s < BB; ++s) c += (cat_ids[s] == t);
        counts[t] = c;
    }
    __syncthreads();
    if (t < NCAT) {
        int off = 0;
        for (int c = 0; c < t; ++c) off += (counts[c] + 3) >> 2;
        const int mt = (counts[t] + 3) >> 2;
        int idx = 0;
        for (int s = 0; s < BB; ++s)
            if (cat_ids[s] == t) msample[off * 4 + (idx++)] = s;
        for (; idx < mt * 4; ++idx) msample[off * 4 + idx] = -1;
        for (int mm = 0; mm < mt; ++mm) mcat[off + mm] = t;
    }
    __syncthreads();
    if (t == 0) {
        int tot = 0;
        for (int c = 0; c < NCAT; ++c) tot += (counts[c] + 3) >> 2;
        for (int mm = tot; mm < MT_MAX; ++mm) mcat[mm] = -1;
    }
}

// ---------------------------------------------------------------------------
// build_x: X[row][0:1536] = actions @ W1[cat] + b1[cat]; X[row][1536:3072] = PE
// ---------------------------------------------------------------------------
__global__ void build_x_kernel(const float* __restrict__ actions,
                               const int* __restrict__ timesteps,
                               const int* __restrict__ cat_ids,
                               const float* __restrict__ W1,
                               const float* __restrict__ b1,
                               unsigned short* __restrict__ X) {
    const int s = blockIdx.x;
    const int part = blockIdx.y;
    const int t = threadIdx.x;
    if (part < 6) {
        const int cat = cat_ids[s];
        const int h = part * 256 + t;
        __shared__ float act[TT][ADIM];
        const float* ab = actions + (size_t)s * TT * ADIM;
        ((float*)act)[t]       = ab[t];
        ((float*)act)[t + 256] = ab[t + 256];
        __syncthreads();
        const float* W1c = W1 + (size_t)cat * ADIM * HID + h;
        float acc[TT];
        #pragma unroll
        for (int r = 0; r < TT; ++r) acc[r] = 0.f;
        #pragma unroll 8
        for (int d = 0; d < ADIM; ++d) {
            const float wv = W1c[(size_t)d * HID];
            #pragma unroll
            for (int r = 0; r < TT; ++r) acc[r] += act[r][d] * wv;
        }
        const float bias = b1[cat * HID + h];
        #pragma unroll
        for (int r = 0; r < TT; ++r)
            X[(size_t)(s * TT + r) * (2 * HID) + h] = f2bf(acc[r] + bias);
    } else {
        const float ts = (float)timesteps[s];
        #pragma unroll
        for (int j = 0; j < 6; ++j) {
            const int i = j * 256 + t;
            const int ii = (i < 768) ? i : i - 768;
            const float freq = expf(-9.210340371976184f * (float)ii * (1.0f / 768.0f));
            const float ang = ts * freq;
            const float v = (i < 768) ? sinf(ang) : cosf(ang);
            const unsigned short bv = f2bf(v);
            for (int r = 0; r < TT; ++r)
                X[(size_t)(s * TT + r) * (2 * HID) + HID + i] = bv;
        }
    }
}

// ---------------------------------------------------------------------------
// gemm_cs2: P[ks][rows][n] = Xtile(bf16) @ W[cat](fp32->bf16)
//   block: 256 thr = 4 waves; tile BM=64 x BN=128 x BK=64; KP=768 per z.
//   LDS layout [k-slot][row][8 bf16]: conflict-free b128 reads/writes.
//   A: global_load_lds (bf16, k-contig). B: reg-staged fp32 columns + cvt.
// ---------------------------------------------------------------------------
template<int K>
__global__ __launch_bounds__(256) void gemm_cs2(
        const unsigned short* __restrict__ Xin,  // [ROWS][K] bf16
        const float* __restrict__ W,             // [NCAT][K][HID] fp32
        const int* __restrict__ msample,
        const int* __restrict__ mcat,
        float* __restrict__ P) {                 // [z][ROWS][HID] fp32
    const int m   = blockIdx.y;
    const int cat = mcat[m];
    if (cat < 0) return;
    const int n0 = blockIdx.x * 128;
    const int ks = blockIdx.z;
    const int k0 = ks * KP;

    const int q  = threadIdx.x;
    const int l  = q & 63;
    const int w  = q >> 6;
    const int wm = w >> 1, wn = w & 1;
    const int col = l & 15, g = l >> 4;

    __shared__ unsigned short Abuf[2][8][64][8];    // 16 KB
    __shared__ unsigned short Bbuf[2][8][128][8];   // 32 KB

    const int s0 = msample[m*4+0], s1 = msample[m*4+1],
              s2 = msample[m*4+2], s3 = msample[m*4+3];

    // A per-lane source: row-in-tile = lane l (f = g, r = col)
    int sA = (g == 0) ? s0 : (g == 1) ? s1 : (g == 2) ? s2 : s3;
    if (sA < 0) sA = 0;
    const unsigned short* aSrc = Xin + ((size_t)sA * TT + col) * K + k0;

    const float* wbase = W + ((size_t)cat * K + k0) * HID + n0;

    f32x4 acc[2][4];
    #pragma unroll
    for (int i = 0; i < 2; ++i)
        #pragma unroll
        for (int j = 0; j < 4; ++j) acc[i][j] = f32x4{0.f, 0.f, 0.f, 0.f};

    float bcol[4][8];

#if __has_builtin(__builtin_amdgcn_global_load_lds)
    auto issueA = [&](int t, int buf) {
        #pragma unroll
        for (int pp = 0; pp < 2; ++pp) {
            const int p = w * 2 + pp;
            __builtin_amdgcn_global_load_lds(
                (const __attribute__((address_space(1))) unsigned int*)(aSrc + t * 64 + p * 8),
                (__attribute__((address_space(3))) unsigned int*)(&Abuf[buf][p][0][0]),
                16, 0, 0);
        }
    };
#else
    // fallback: reg-stage A. thread: row = q>>2, slots (q&3)+4*it
    const int rowF = q >> 2;
    int sF = (w == 0) ? s0 : (w == 1) ? s1 : (w == 2) ? s2 : s3;   // f = row>>4 = w
    if (sF < 0) sF = 0;
    const unsigned short* aSrcF = Xin + ((size_t)sF * TT + (rowF & 15)) * K + k0;
    auto issueA = [&](int t, int buf) {
        #pragma unroll
        for (int it = 0; it < 2; ++it) {
            const int slot = (q & 3) + it * 4;
            bf16x8 av = *(const bf16x8*)(aSrcF + t * 64 + slot * 8);
            *(bf16x8*)(&Abuf[buf][slot][rowF][0]) = av;
        }
    };
#endif

    auto loadB = [&](int t) {
        #pragma unroll
        for (int it = 0; it < 4; ++it) {
            const int c = q + it * 256;
            const int n = c & 127, slot = c >> 7;
            const float* wc = wbase + ((size_t)t * 64 + slot * 8) * HID + n;
            #pragma unroll
            for (int dk = 0; dk < 8; ++dk) bcol[it][dk] = wc[(size_t)dk * HID];
        }
    };
    auto cvtWriteB = [&](int buf) {
        #pragma unroll
        for (int it = 0; it < 4; ++it) {
            const int c = q + it * 256;
            const int n = c & 127, slot = c >> 7;
            bf16x8 v;
            #pragma unroll
            for (int dk = 0; dk < 8; ++dk) v[dk] = (short)f2bf(bcol[it][dk]);
            *(bf16x8*)(&Bbuf[buf][slot][n][0]) = v;
        }
    };
    auto compute = [&](int buf) {
        #pragma unroll
        for (int kc = 0; kc < 2; ++kc) {
            const int sl = kc * 4 + g;
            const bf16x8 a0 = *(const bf16x8*)(&Abuf[buf][sl][wm * 32 + col][0]);
            const bf16x8 a1 = *(const bf16x8*)(&Abuf[buf][sl][wm * 32 + 16 + col][0]);
            #pragma unroll
            for (int nf = 0; nf < 4; ++nf) {
                const bf16x8 bb = *(const bf16x8*)(&Bbuf[buf][sl][wn * 64 + nf * 16 + col][0]);
                acc[0][nf] = __builtin_amdgcn_mfma_f32_16x16x32_bf16(a0, bb, acc[0][nf], 0, 0, 0);
                acc[1][nf] = __builtin_amdgcn_mfma_f32_16x16x32_bf16(a1, bb, acc[1][nf], 0, 0, 0);
            }
        }
    };

    // pipeline: stage t+1 while computing t; one barrier per K-step
    issueA(0, 0);
    loadB(0);
    cvtWriteB(0);
    __syncthreads();
    for (int t = 0; t < NTILES - 1; ++t) {
        const int cur = t & 1, nxt = cur ^ 1;
        loadB(t + 1);          // issue global loads early (hide under MFMA)
        issueA(t + 1, nxt);
        compute(cur);
        cvtWriteB(nxt);
        __syncthreads();
    }
    compute((NTILES - 1) & 1);

    // epilogue: D row = g*4+j, col = l&15
    const int sE0 = wm ? s2 : s0;
    const int sE1 = wm ? s3 : s1;
    #pragma unroll
    for (int mf = 0; mf < 2; ++mf) {
        const int s = mf ? sE1 : sE0;
        if (s < 0) continue;
        float* prow = P + ((size_t)ks * ROWS + (size_t)s * TT + g * 4) * HID
                        + n0 + wn * 64 + col;
        #pragma unroll
        for (int nf = 0; nf < 4; ++nf)
            #pragma unroll
            for (int j = 0; j < 4; ++j)
                prow[(size_t)j * HID + nf * 16] = acc[mf][nf][j];
    }
}

// ---------------------------------------------------------------------------
// finish: out = [swish](sum_s P[s] + bias[cat])
// ---------------------------------------------------------------------------
template<int S, bool DOSWISH, bool BF16OUT>
__global__ void finish_kernel(const float* __restrict__ P,
                              const float* __restrict__ bias,
                              const int* __restrict__ cat_ids,
                              void* __restrict__ out) {
    const int idx = blockIdx.x * 256 + threadIdx.x;
    const int i4 = idx * 4;
    const int row = i4 / HID;
    const int colb = i4 - row * HID;
    const int cat = cat_ids[row >> 4];
    float4 v = *(const float4*)(P + i4);
    #pragma unroll
    for (int s2 = 1; s2 < S; ++s2) {
        const float4 p = *(const float4*)(P + (size_t)s2 * ROWS * HID + i4);
        v.x += p.x; v.y += p.y; v.z += p.z; v.w += p.w;
    }
    const float4 bv = *(const float4*)(bias + (size_t)cat * HID + colb);
    v.x += bv.x; v.y += bv.y; v.z += bv.z; v.w += bv.w;
    if (DOSWISH) {
        v.x = v.x / (1.f + __expf(-v.x));
        v.y = v.y / (1.f + __expf(-v.y));
        v.z = v.z / (1.f + __expf(-v.z));
        v.w = v.w / (1.f + __expf(-v.w));
    }
    if (BF16OUT) {
        uint2 u;
        u.x = (unsigned)f2bf(v.x) | ((unsigned)f2bf(v.y) << 16);
        u.y = (unsigned)f2bf(v.z) | ((unsigned)f2bf(v.w) << 16);
        *(uint2*)((unsigned short*)out + i4) = u;
    } else {
        *(float4*)((float*)out + i4) = v;
    }
}

// ---------------------------------------------------------------------------
extern "C" void kernel_launch(void* const* d_in, const int* in_sizes, int n_in,
                              void* d_out, int out_size, void* d_ws, size_t ws_size,
                              hipStream_t stream) {
    const float* actions   = (const float*)d_in[0];
    const int*   timesteps = (const int*)d_in[1];
    const int*   cat_ids   = (const int*)d_in[2];
    const float* W1        = (const float*)d_in[3];
    const float* b1        = (const float*)d_in[4];
    const float* W2        = (const float*)d_in[5];
    const float* b2        = (const float*)d_in[6];
    const float* W3        = (const float*)d_in[7];
    const float* b3        = (const float*)d_in[8];

    char* ws = (char*)d_ws;
    unsigned short* X = (unsigned short*)ws;                 // 6,291,456 B
    unsigned short* H = (unsigned short*)(ws + 6291456);     // 3,145,728 B
    float* P          = (float*)(ws + 9437184);              // 25,165,824 B
    int* msample      = (int*)(ws + 34603008);
    int* mcat         = msample + MT_MAX * 4;

    prep_kernel<<<1, 64, 0, stream>>>(cat_ids, msample, mcat);
    build_x_kernel<<<dim3(BB, 7), 256, 0, stream>>>(actions, timesteps, cat_ids, W1, b1, X);

    gemm_cs2<2 * HID><<<dim3(HID / 128, MT_MAX, 4), 256, 0, stream>>>(
        X, W2, msample, mcat, P);
    finish_kernel<4, true, true><<<ROWS * HID / 4 / 256, 256, 0, stream>>>(
        P, b2, cat_ids, H);

    gemm_cs2<HID><<<dim3(HID / 128, MT_MAX, 2), 256, 0, stream>>>(
        H, W3, msample, mcat, P);
    finish_kernel<2, false, false><<<ROWS * HID / 4 / 256, 256, 0, stream>>>(
        P, b3, cat_ids, d_out);
}

// Round 4
// 119.625 us; speedup vs baseline: 1.0353x; 1.0353x over previous
//
#include <hip/hip_runtime.h>
#include <hip/hip_bf16.h>

#define BB 64
#define TT 16
#define ROWS 1024
#define ADIM 32
#define HID 1536
#define NCAT 4
#define MT_MAX 20          // worst case sum ceil(cnt_c/4) = 19

typedef __attribute__((ext_vector_type(8))) short bf16x8;
typedef __attribute__((ext_vector_type(4))) float f32x4;

static __device__ __forceinline__ unsigned short f2bf(float f) {
    union { float f; unsigned int u; } v; v.f = f;
    unsigned int u = v.u + 0x7fff + ((v.u >> 16) & 1);   // RNE
    return (unsigned short)(u >> 16);
}

// ---------------------------------------------------------------------------
// prep: group samples by category into padded 4-sample m-tiles.
// ---------------------------------------------------------------------------
__global__ void prep_kernel(const int* __restrict__ cat_ids,
                            int* __restrict__ msample, int* __restrict__ mcat) {
    __shared__ int counts[NCAT];
    const int t = threadIdx.x;
    if (t < NCAT) {
        int c = 0;
        for (int s = 0; s < BB; ++s) c += (cat_ids[s] == t);
        counts[t] = c;
    }
    __syncthreads();
    if (t < NCAT) {
        int off = 0;
        for (int c = 0; c < t; ++c) off += (counts[c] + 3) >> 2;
        const int mt = (counts[t] + 3) >> 2;
        int idx = 0;
        for (int s = 0; s < BB; ++s)
            if (cat_ids[s] == t) msample[off * 4 + (idx++)] = s;
        for (; idx < mt * 4; ++idx) msample[off * 4 + idx] = -1;
        for (int mm = 0; mm < mt; ++mm) mcat[off + mm] = t;
    }
    __syncthreads();
    if (t == 0) {
        int tot = 0;
        for (int c = 0; c < NCAT; ++c) tot += (counts[c] + 3) >> 2;
        for (int mm = tot; mm < MT_MAX; ++mm) mcat[mm] = -1;
    }
}

// ---------------------------------------------------------------------------
// build_x: X[row][0:1536] = actions @ W1[cat] + b1[cat]; X[row][1536:3072] = PE
// ---------------------------------------------------------------------------
__global__ void build_x_kernel(const float* __restrict__ actions,
                               const int* __restrict__ timesteps,
                               const int* __restrict__ cat_ids,
                               const float* __restrict__ W1,
                               const float* __restrict__ b1,
                               unsigned short* __restrict__ X) {
    const int s = blockIdx.x;
    const int part = blockIdx.y;
    const int t = threadIdx.x;
    if (part < 6) {
        const int cat = cat_ids[s];
        const int h = part * 256 + t;
        __shared__ float act[TT][ADIM];
        const float* ab = actions + (size_t)s * TT * ADIM;
        ((float*)act)[t]       = ab[t];
        ((float*)act)[t + 256] = ab[t + 256];
        __syncthreads();
        const float* W1c = W1 + (size_t)cat * ADIM * HID + h;
        float acc[TT];
        #pragma unroll
        for (int r = 0; r < TT; ++r) acc[r] = 0.f;
        #pragma unroll 8
        for (int d = 0; d < ADIM; ++d) {
            const float wv = W1c[(size_t)d * HID];
            #pragma unroll
            for (int r = 0; r < TT; ++r) acc[r] += act[r][d] * wv;
        }
        const float bias = b1[cat * HID + h];
        #pragma unroll
        for (int r = 0; r < TT; ++r)
            X[(size_t)(s * TT + r) * (2 * HID) + h] = f2bf(acc[r] + bias);
    } else {
        const float ts = (float)timesteps[s];
        #pragma unroll
        for (int j = 0; j < 6; ++j) {
            const int i = j * 256 + t;
            const int ii = (i < 768) ? i : i - 768;
            const float freq = expf(-9.210340371976184f * (float)ii * (1.0f / 768.0f));
            const float ang = ts * freq;
            const float v = (i < 768) ? sinf(ang) : cosf(ang);
            const unsigned short bv = f2bf(v);
            for (int r = 0; r < TT; ++r)
                X[(size_t)(s * TT + r) * (2 * HID) + HID + i] = bv;
        }
    }
}

// ---------------------------------------------------------------------------
// gemm_sw: single-wave 64x64 tile, deep register prefetch, NO LDS, NO barriers.
//   A: X rows (bf16, k-contiguous) -> per-lane dwordx4 frags, 3-stage.
//   B: W fp32 strided dwords -> 3-stage reg pipeline -> cvt bf16 -> MFMA.
//   Partials to P[ks] (fp32).
// ---------------------------------------------------------------------------
template<int K, int KSPLIT>
__global__ __launch_bounds__(64, 2) void gemm_sw(
        const unsigned short* __restrict__ Xin,  // [ROWS][K] bf16
        const float* __restrict__ W,             // [NCAT][K][HID] fp32
        const int* __restrict__ msample,
        const int* __restrict__ mcat,
        float* __restrict__ P) {                 // [ks][ROWS][HID] fp32
    constexpr int KP = K / KSPLIT;
    constexpr int NT = KP / 32;                  // must be divisible by 3
    static_assert(NT % 3 == 0, "NT must be divisible by 3");

    const int m   = blockIdx.y;
    const int cat = mcat[m];
    if (cat < 0) return;
    const int n0 = blockIdx.x * 64;
    const int ks = blockIdx.z;
    const int k0 = ks * KP;

    const int l   = threadIdx.x;
    const int col = l & 15;
    const int g   = l >> 4;

    int sidx[4];
    #pragma unroll
    for (int f = 0; f < 4; ++f) sidx[f] = msample[m * 4 + f];

    const unsigned short* aptr[4];
    #pragma unroll
    for (int f = 0; f < 4; ++f) {
        const int s = sidx[f] < 0 ? 0 : sidx[f];
        aptr[f] = Xin + ((size_t)s * TT + col) * K + k0 + g * 8;
    }
    const float* wptr = W + ((size_t)cat * K + k0 + g * 8) * HID + n0 + col;

    f32x4 acc[4][4];
    #pragma unroll
    for (int i = 0; i < 4; ++i)
        #pragma unroll
        for (int j = 0; j < 4; ++j) acc[i][j] = f32x4{0.f, 0.f, 0.f, 0.f};

    // 3-stage pipelines (all indices static after unroll -> registers)
    float  bs[3][32];
    bf16x8 as[3][4];

    auto issueB = [&](int t, int s) {
        const int tc = (t < NT) ? t : NT - 1;
        #pragma unroll
        for (int nf = 0; nf < 4; ++nf)
            #pragma unroll
            for (int j = 0; j < 8; ++j)
                bs[s][nf * 8 + j] = wptr[(size_t)(tc * 32 + j) * HID + nf * 16];
    };
    auto issueA = [&](int t, int s) {
        const int tc = (t < NT) ? t : NT - 1;
        #pragma unroll
        for (int f = 0; f < 4; ++f)
            as[s][f] = *(const bf16x8*)(aptr[f] + tc * 32);
    };
    auto step = [&](int s) {
        bf16x8 bfr[4];
        #pragma unroll
        for (int nf = 0; nf < 4; ++nf)
            #pragma unroll
            for (int j = 0; j < 8; ++j)
                bfr[nf][j] = (short)f2bf(bs[s][nf * 8 + j]);
        #pragma unroll
        for (int mf = 0; mf < 4; ++mf)
            #pragma unroll
            for (int nf = 0; nf < 4; ++nf)
                acc[mf][nf] = __builtin_amdgcn_mfma_f32_16x16x32_bf16(
                    as[s][mf], bfr[nf], acc[mf][nf], 0, 0, 0);
    };

    // prologue: fill stages 0,1
    issueB(0, 0); issueA(0, 0);
    issueB(1, 1); issueA(1, 1);

    for (int tt = 0; tt < NT; tt += 3) {
        // t = tt+0: compute stage 0, prefetch t+2 -> stage 2
        issueB(tt + 2, 2); issueA(tt + 2, 2);
        step(0);
        // t = tt+1: compute stage 1, prefetch t+2 -> stage 0
        issueB(tt + 3, 0); issueA(tt + 3, 0);
        step(1);
        // t = tt+2: compute stage 2, prefetch t+2 -> stage 1
        issueB(tt + 4, 1); issueA(tt + 4, 1);
        step(2);
    }

    // epilogue: D row = g*4 + r, col = l&15  (verified mapping from R1/R2)
    #pragma unroll
    for (int mf = 0; mf < 4; ++mf) {
        if (sidx[mf] < 0) continue;
        float* prow = P + ((size_t)ks * ROWS + (size_t)sidx[mf] * TT + g * 4) * HID
                        + n0 + col;
        #pragma unroll
        for (int nf = 0; nf < 4; ++nf)
            #pragma unroll
            for (int r = 0; r < 4; ++r)
                prow[(size_t)r * HID + nf * 16] = acc[mf][nf][r];
    }
}

// ---------------------------------------------------------------------------
// finish: out = [swish](sum_s P[s] + bias[cat])
// ---------------------------------------------------------------------------
template<int S, bool DOSWISH, bool BF16OUT>
__global__ void finish_kernel(const float* __restrict__ P,
                              const float* __restrict__ bias,
                              const int* __restrict__ cat_ids,
                              void* __restrict__ out) {
    const int idx = blockIdx.x * 256 + threadIdx.x;
    const int i4 = idx * 4;
    const int row = i4 / HID;
    const int colb = i4 - row * HID;
    const int cat = cat_ids[row >> 4];
    float4 v = *(const float4*)(P + i4);
    #pragma unroll
    for (int s2 = 1; s2 < S; ++s2) {
        const float4 p = *(const float4*)(P + (size_t)s2 * ROWS * HID + i4);
        v.x += p.x; v.y += p.y; v.z += p.z; v.w += p.w;
    }
    const float4 bv = *(const float4*)(bias + (size_t)cat * HID + colb);
    v.x += bv.x; v.y += bv.y; v.z += bv.z; v.w += bv.w;
    if (DOSWISH) {
        v.x = v.x / (1.f + __expf(-v.x));
        v.y = v.y / (1.f + __expf(-v.y));
        v.z = v.z / (1.f + __expf(-v.z));
        v.w = v.w / (1.f + __expf(-v.w));
    }
    if (BF16OUT) {
        uint2 u;
        u.x = (unsigned)f2bf(v.x) | ((unsigned)f2bf(v.y) << 16);
        u.y = (unsigned)f2bf(v.z) | ((unsigned)f2bf(v.w) << 16);
        *(uint2*)((unsigned short*)out + i4) = u;
    } else {
        *(float4*)((float*)out + i4) = v;
    }
}

// ---------------------------------------------------------------------------
extern "C" void kernel_launch(void* const* d_in, const int* in_sizes, int n_in,
                              void* d_out, int out_size, void* d_ws, size_t ws_size,
                              hipStream_t stream) {
    const float* actions   = (const float*)d_in[0];
    const int*   timesteps = (const int*)d_in[1];
    const int*   cat_ids   = (const int*)d_in[2];
    const float* W1        = (const float*)d_in[3];
    const float* b1        = (const float*)d_in[4];
    const float* W2        = (const float*)d_in[5];
    const float* b2        = (const float*)d_in[6];
    const float* W3        = (const float*)d_in[7];
    const float* b3        = (const float*)d_in[8];

    char* ws = (char*)d_ws;
    unsigned short* X = (unsigned short*)ws;                 // 6,291,456 B
    unsigned short* H = (unsigned short*)(ws + 6291456);     // 3,145,728 B
    float* P          = (float*)(ws + 9437184);              // 25,165,824 B
    int* msample      = (int*)(ws + 34603008);
    int* mcat         = msample + MT_MAX * 4;

    prep_kernel<<<1, 64, 0, stream>>>(cat_ids, msample, mcat);
    build_x_kernel<<<dim3(BB, 7), 256, 0, stream>>>(actions, timesteps, cat_ids, W1, b1, X);

    // GEMM2: K=3072, KSPLIT=4 -> KP=768, NT=24
    gemm_sw<2 * HID, 4><<<dim3(HID / 64, MT_MAX, 4), 64, 0, stream>>>(
        X, W2, msample, mcat, P);
    finish_kernel<4, true, true><<<ROWS * HID / 4 / 256, 256, 0, stream>>>(
        P, b2, cat_ids, H);

    // GEMM3: K=1536, KSPLIT=2 -> KP=768, NT=24
    gemm_sw<HID, 2><<<dim3(HID / 64, MT_MAX, 2), 64, 0, stream>>>(
        H, W3, msample, mcat, P);
    finish_kernel<2, false, false><<<ROWS * HID / 4 / 256, 256, 0, stream>>>(
        P, b3, cat_ids, d_out);
}